// Round 10
// baseline (36.298 us; speedup 1.0000x reference)
//
#include <hip/hip_runtime.h>
#include <hip/hip_bf16.h>

#define B_   32
#define N_   128
#define AH_  512
#define AW_  512
#define LCAP 64    // per-chunk list capacity (one 64-box ballot chunk)

// compiler-only reordering fence; one wave's DS ops execute in issue order
#define CFENCE() asm volatile("" ::: "memory")

// ---------------------------------------------------------------------------
// R10 = R6 (best, 29.4us) with LOAD-BALANCED row pairing.
//
// Diagnosis: 8192 waves = exactly one resident generation; rows y>~424 have
// no boxes (light), rows ~100..400 are box-dense (heavy). With consecutive-
// row pairing every heavy wave pairs 2 heavy rows -> kernel time = max-wave
// time; R5's counters showed the signature (VALUBusy 49%, time-avg Occ 38%).
// Fix: task i handles rows {i, 511-i} -- heavy+light pairs, ~uniform work.
// Body is byte-for-byte R6's proven structure (2 independent waves/block,
// no barriers, LDS box list + [2][512] mask, prefetched raster, gated logs).
// ---------------------------------------------------------------------------
__global__ __launch_bounds__(128) void row_bce_kernel(
    const float* __restrict__ att,
    const float* __restrict__ bboxs,
    const int*   __restrict__ img_h_p,
    const int*   __restrict__ img_w_p,
    float*       __restrict__ wave_sums)
{
    const int t    = threadIdx.x;
    const int lane = t & 63;
    const int wid  = t >> 6;                    // 0..1
    const int task = (blockIdx.x << 1) | wid;   // 0..8191
    const int b    = task >> 8;                 // 256 tasks per image
    const int i    = task & 255;
    const int yA   = i;                         // heavy half (top)
    const int yB   = (AH_ - 1) - i;             // light half (bottom)

    __shared__ float4 s_geo[2][LCAP];           // {pack(x1,x2,ab), x1m, x2m, -}
    __shared__ float2 s_rv [2][LCAP];           // {rowv(yA), rowv(yB)}
    __shared__ float  s_mask[2][2][AW_];        // [wid][rowslot][x]

    const float fw  = (float)(*img_w_p);
    const float fh  = (float)(*img_h_p);
    const float sxs = (float)AW_ / fw;
    const float sys = (float)AH_ / fh;

    // ---- hoisted attention loads (rows yA and yB) ----
    const float4* pA = (const float4*)(att + ((size_t)b * AH_ + yA) * AW_);
    const float4* pB = (const float4*)(att + ((size_t)b * AH_ + yB) * AW_);
    float4 P[2][2];
    #pragma unroll
    for (int h = 0; h < 2; ++h) {
        P[0][h] = pA[h * 64 + lane];
        P[1][h] = pB[h * 64 + lane];
    }

    // ---- box geometry, once per wave (boxes lane and lane+64) ----
    bool  act_any[2];
    int   actb[2];
    int   gx1[2], gx2[2];
    float gx1m[2], gx2m[2];
    float rvA[2], rvB[2];
    #pragma unroll
    for (int k = 0; k < 2; ++k) {
        const int n = lane + 64 * k;
        const float* bp = bboxs + ((size_t)b * N_ + n) * 5;
        const float c0 = bp[0], c1 = bp[1], c2 = bp[2], c3 = bp[3], lab = bp[4];
        const bool valid = (lab != -1.0f) && (c0 <= fw) && (c1 <= fh)
                                          && (c2 <= fw) && (c3 <= fh);
        const float bx1 = c0 * sxs, by1 = c1 * sys;
        const float bx2 = c2 * sxs, by2 = c3 * sys;
        const float fx1 = floorf(bx1), fy1 = floorf(by1);
        const float x1m = fx1 + 1.0f - bx1;
        const float y1m = fy1 + 1.0f - by1;
        const float x2m = bx2 - floorf(bx2);
        const float y2m = by2 - floorf(by2);
        const int x1 = (int)fmaxf(fx1, 0.0f);
        const int y1 = (int)fmaxf(fy1, 0.0f);
        const int x2 = (int)fminf(ceilf(bx2) + 1.0f, (float)AW_);
        const int y2 = (int)fminf(ceilf(by2) + 1.0f, (float)AH_);
        gx1[k] = x1; gx2[k] = x2; gx1m[k] = x1m; gx2m[k] = x2m;

        const bool aA = valid && (yA >= y1) && (yA < y2);
        const bool aB = valid && (yB >= y1) && (yB < y2);
        rvA[k] = ((yA == y1) ? y1m : 1.0f) * ((yA == y2 - 1) ? y2m : 1.0f);
        rvB[k] = ((yB == y1) ? y1m : 1.0f) * ((yB == y2 - 1) ? y2m : 1.0f);
        actb[k]    = (aA ? 1 : 0) | (aB ? 2 : 0);
        act_any[k] = (actb[k] != 0);
    }

    const unsigned long long ltm  = (1ull << lane) - 1ull;
    const unsigned long long bal0 = __ballot(act_any[0]);
    const unsigned long long bal1 = __ballot(act_any[1]);
    const bool have = (bal0 | bal1) != 0ull;

    float* m0 = s_mask[wid][0];     // slot0 = row yA; slot1 = m0+512 = row yB
    float* m1 = m0 + AW_;
    float4* mrow4 = (float4*)m0;

    if (have) {
        // zero both mask rows: 4x ds_write_b128 per lane
        const float4 z = make_float4(0.f, 0.f, 0.f, 0.f);
        #pragma unroll
        for (int q = 0; q < 4; ++q) mrow4[lane + 64 * q] = z;
        CFENCE();

        // ---- two 64-box chunks in index order; list buffer reused ----
        #pragma unroll
        for (int k = 0; k < 2; ++k) {
            const unsigned long long bal = (k == 0) ? bal0 : bal1;
            const int cnt = __popcll(bal);
            if (cnt == 0) continue;
            if (act_any[k]) {
                const int slot = __popcll(bal & ltm);
                s_geo[wid][slot] = make_float4(
                    __int_as_float(gx1[k] | (gx2[k] << 10) | (actb[k] << 20)),
                    gx1m[k], gx2m[k], 0.0f);
                s_rv[wid][slot] = make_float2(rvA[k], rvB[k]);
            }
            CFENCE();   // compaction writes precede list reads (in-order DS)

            // raster with 1-deep prefetch
            float4 g_cur = s_geo[wid][0];
            float2 v_cur = s_rv[wid][0];
            for (int j = 0; j < cnt; ++j) {
                const float4 g = g_cur;
                const float2 v = v_cur;
                if (j + 1 < cnt) {
                    g_cur = s_geo[wid][j + 1];
                    v_cur = s_rv[wid][j + 1];
                }
                const int px = __float_as_int(g.x);
                const int e1 = px & 1023;
                const int e2 = (px >> 10) & 1023;
                const int ab = px >> 20;
                for (int x = e1 + lane; x < e2; x += 64) {
                    const float edge = ((x == e1)     ? g.y : 1.0f)
                                     * ((x == e2 - 1) ? g.z : 1.0f);
                    if (ab & 1) m0[x] = v.x * edge;
                    if (ab & 2) m1[x] = v.y * edge;
                }
            }
            CFENCE();   // this chunk's raster reads precede next compaction
        }
    }

    // ---- BCE over rows yA,yB (p in [1e-4,1-1e-4]: no clamps) ----
    float acc = 0.0f;
    #pragma unroll
    for (int r = 0; r < 2; ++r) {
        #pragma unroll
        for (int h = 0; h < 2; ++h) {
            const float4 p = P[r][h];
            float4 m = make_float4(0.f, 0.f, 0.f, 0.f);
            if (have) m = mrow4[r * 128 + h * 64 + lane];
            const float pv[4] = {p.x, p.y, p.z, p.w};
            const float mv[4] = {m.x, m.y, m.z, m.w};
            const bool nz = (m.x != 0.f) | (m.y != 0.f)
                          | (m.z != 0.f) | (m.w != 0.f);
            if (__any(nz)) {
                #pragma unroll
                for (int j = 0; j < 4; ++j) {
                    const float lp = __logf(pv[j]);
                    const float l1 = __logf(1.0f - pv[j]);
                    acc += l1 + mv[j] * (lp - l1);
                }
            } else {
                #pragma unroll
                for (int j = 0; j < 4; ++j)
                    acc += __logf(1.0f - pv[j]);
            }
        }
    }

    // ---- wave reduction -> per-task partial ----
    #pragma unroll
    for (int off = 32; off; off >>= 1) acc += __shfl_down(acc, off, 64);
    if (lane == 0) wave_sums[task] = acc;
}

// ---------------------------------------------------------------------------
// Fused tail: per-image reduce of 256 task partials + any_valid gate +
// batch mean. One block, 1024 threads (32 workers per image).
// ---------------------------------------------------------------------------
__global__ __launch_bounds__(1024) void final_kernel(
    const float* __restrict__ bboxs,
    const int*   __restrict__ img_h_p,
    const int*   __restrict__ img_w_p,
    const float* __restrict__ wave_sums,
    float*       __restrict__ out)
{
    const int t = threadIdx.x;
    const int b = t >> 5;        // image 0..31
    const int j = t & 31;        // worker within image

    __shared__ float s_sum[1024];
    __shared__ int   s_any[1024];
    __shared__ float s_loss[B_];

    float s = 0.0f;
    #pragma unroll
    for (int k = 0; k < 8; ++k) s += wave_sums[b * 256 + j + 32 * k];
    s_sum[t] = s;

    const float fw = (float)(*img_w_p);
    const float fh = (float)(*img_h_p);
    int av = 0;
    const float* bp = bboxs + (size_t)b * N_ * 5;
    #pragma unroll
    for (int n = j * 4; n < j * 4 + 4; ++n) {
        const float c0 = bp[n * 5 + 0];
        const float c1 = bp[n * 5 + 1];
        const float c2 = bp[n * 5 + 2];
        const float c3 = bp[n * 5 + 3];
        const float lab = bp[n * 5 + 4];
        av |= ((lab != -1.0f) && (c0 <= fw) && (c1 <= fh)
                              && (c2 <= fw) && (c3 <= fh)) ? 1 : 0;
    }
    s_any[t] = av;
    __syncthreads();

    if (j == 0) {
        float sum = 0.0f;
        int anyv = 0;
        for (int k = 0; k < 32; ++k) {
            sum  += s_sum[b * 32 + k];
            anyv |= s_any[b * 32 + k];
        }
        s_loss[b] = anyv ? (-sum * (1.0f / (float)(AH_ * AW_))) : 0.0f;
    }
    __syncthreads();

    if (t == 0) {
        float total = 0.0f;
        for (int k = 0; k < B_; ++k) total += s_loss[k];
        out[0] = total * (1.0f / (float)B_);
    }
}

extern "C" void kernel_launch(void* const* d_in, const int* in_sizes, int n_in,
                              void* d_out, int out_size, void* d_ws, size_t ws_size,
                              hipStream_t stream)
{
    const float* att   = (const float*)d_in[0];   // (32,1,512,512) f32
    const float* bboxs = (const float*)d_in[1];   // (32,128,5) f32
    const int*   img_h = (const int*)d_in[2];     // scalar
    const int*   img_w = (const int*)d_in[3];     // scalar
    float* out = (float*)d_out;
    float* wave_sums = (float*)d_ws;              // 8192 floats (32 KB)

    row_bce_kernel<<<B_ * AH_ / 4, 128, 0, stream>>>(att, bboxs, img_h, img_w, wave_sums);
    final_kernel<<<1, 1024, 0, stream>>>(bboxs, img_h, img_w, wave_sums, out);
}